// Round 13
// baseline (113.347 us; speedup 1.0000x reference)
//
#include <hip/hip_runtime.h>
#include <math.h>

#define BB 4
#define ND 256
#define NE 512
#define CC 256

#define K2E 2.8853900817779268f   // 2 * log2(e): exp2(K2E*x) = e^{2x}
#define LOG2E 1.4426950408889634f
#define LN2 0.6931471805599453f

typedef unsigned int u32;
typedef unsigned short u16;

__device__ __forceinline__ u16 f2bf(float f) {   // RTNE float->bf16
    u32 u = __builtin_bit_cast(u32, f);
    u += 0x7fffu + ((u >> 16) & 1u);
    return (u16)(u >> 16);
}
__device__ __forceinline__ float bflo(u32 u) { return __builtin_bit_cast(float, u << 16); }
__device__ __forceinline__ float bfhi(u32 u) { return __builtin_bit_cast(float, u & 0xffff0000u); }

// ---------------------------------------------------------------------------
// MEASUREMENT ROUND: both kernels run their body 4x internally (idempotent)
// so their dispatches out-rank the harness's ~40us poison-fills in the top-5
// counter table. Logic identical to R12 otherwise.
// ---------------------------------------------------------------------------
__global__ __launch_bounds__(256) void proj_kernel(
    const float* __restrict__ xdec, const float* __restrict__ xenc,
    const float* __restrict__ w1,   const float* __restrict__ w2,
    uint4* __restrict__ Et4, float* __restrict__ Dexp)
{
    __shared__ float Xs[16][36];
    __shared__ float Ws[16][68];
    __shared__ u32   T[32][33];

    const int row0 = blockIdx.x * 32;
    const int col0 = blockIdx.y * 64;
    const bool is_enc = (row0 < BB * NE);

    const float* X = is_enc ? xenc : xdec;
    const float* W = is_enc ? w1   : w2;
    const int xrow0 = is_enc ? row0 : (row0 - BB * NE);

    const int tid = threadIdx.x;
    const int xr = tid >> 3, xk = (tid & 7) * 2;
    const int wc = tid >> 2, wk = (tid & 3) * 4;
    const int ty = tid >> 5;
    const int tx = tid & 31;

#pragma unroll 1
    for (int rep = 0; rep < 4; ++rep) {
        float acc[4][2] = {};

        float2 xv = *(const float2*)&X[(xrow0 + xr) * CC + xk];
        float4 wv = *(const float4*)&W[(col0 + wc) * CC + wk];

        for (int k0 = 0; k0 < CC; k0 += 16) {
            __syncthreads();
            Xs[xk][xr] = xv.x; Xs[xk + 1][xr] = xv.y;
            Ws[wk][wc] = wv.x; Ws[wk + 1][wc] = wv.y;
            Ws[wk + 2][wc] = wv.z; Ws[wk + 3][wc] = wv.w;
            __syncthreads();
            if (k0 + 16 < CC) {
                xv = *(const float2*)&X[(xrow0 + xr) * CC + k0 + 16 + xk];
                wv = *(const float4*)&W[(col0 + wc) * CC + k0 + 16 + wk];
            }
#pragma unroll
            for (int k = 0; k < 16; ++k) {
                float4 a = *(const float4*)&Xs[k][ty * 4];
                float2 b = *(const float2*)&Ws[k][tx * 2];
                acc[0][0] += a.x * b.x; acc[0][1] += a.x * b.y;
                acc[1][0] += a.y * b.x; acc[1][1] += a.y * b.y;
                acc[2][0] += a.z * b.x; acc[2][1] += a.z * b.y;
                acc[3][0] += a.w * b.x; acc[3][1] += a.w * b.y;
            }
        }

        float ex[4][2];
#pragma unroll
        for (int i = 0; i < 4; ++i)
#pragma unroll
            for (int j = 0; j < 2; ++j)
                ex[i][j] = __builtin_amdgcn_exp2f(
                    K2E * fminf(fmaxf(acc[i][j], -9.f), 9.f));

        if (is_enc) {
#pragma unroll
            for (int i = 0; i < 4; ++i)
                T[tx][ty * 4 + i] = (u32)f2bf(ex[i][0]) | ((u32)f2bf(ex[i][1]) << 16);
            __syncthreads();
            const int b   = row0 >> 9;
            const int e0  = row0 & 511;
            const int eL  = tid & 31;
            const int cqL = tid >> 5;
            const int cq0 = col0 >> 3;
            uint4 w4;
            w4.x = T[cqL * 4 + 0][eL];
            w4.y = T[cqL * 4 + 1][eL];
            w4.z = T[cqL * 4 + 2][eL];
            w4.w = T[cqL * 4 + 3][eL];
            Et4[((size_t)b * 32 + cq0 + cqL) * 512 + e0 + eL] = w4;
        } else {
#pragma unroll
            for (int i = 0; i < 4; ++i) {
                float2 o = make_float2(ex[i][0], ex[i][1]);
                *(float2*)&Dexp[(size_t)(xrow0 + ty * 4 + i) * CC + col0 + tx * 2] = o;
            }
        }
        __syncthreads();   // protect Xs/Ws/T reuse across reps
    }
}

// ---------------------------------------------------------------------------
__global__ __launch_bounds__(512) void attn_kernel(
    const uint4* __restrict__ Et4, const float* __restrict__ Dexp,
    const float* __restrict__ v, float* __restrict__ out)
{
    __shared__ float prod[2][NE];

    const int blk = blockIdx.x;       // 0..511
    const int b   = blk >> 7;
    const int n0  = (blk & 127) * 2;
    const int tid = threadIdx.x;      // == e

    const float* __restrict__ D0 = Dexp + (size_t)(b * ND + n0) * CC;
    const float* __restrict__ D1 = D0 + CC;
    const uint4* Ec = Et4 + (size_t)b * 32 * 512 + tid;

#define PAIR(ACC, E0, E1, V0, V1, Dx0, Dx1) do {                             \
        const float _d0 = fmaf((E0), (Dx0), 1.0f);                           \
        const float _d1 = fmaf((E1), (Dx1), 1.0f);                           \
        const float _num = fmaf((V1), _d0, (V0) * _d1);                      \
        ACC = fmaf(_num, __builtin_amdgcn_rcpf(_d0 * _d1), ACC);             \
    } while (0)

#define PROC(E4, CQ) do {                                                    \
        const int c8 = (CQ) * 8;                                             \
        const float4 vA  = *(const float4*)&v [c8];                          \
        const float4 vB  = *(const float4*)&v [c8 + 4];                      \
        const float4 dA0 = *(const float4*)&D0[c8];                          \
        const float4 dB0 = *(const float4*)&D0[c8 + 4];                      \
        const float4 dA1 = *(const float4*)&D1[c8];                          \
        const float4 dB1 = *(const float4*)&D1[c8 + 4];                      \
        PAIR(a0, bflo(E4.x), bfhi(E4.x), vA.x, vA.y, dA0.x, dA0.y);          \
        PAIR(a1, bflo(E4.x), bfhi(E4.x), vA.x, vA.y, dA1.x, dA1.y);          \
        PAIR(a0, bflo(E4.y), bfhi(E4.y), vA.z, vA.w, dA0.z, dA0.w);          \
        PAIR(a1, bflo(E4.y), bfhi(E4.y), vA.z, vA.w, dA1.z, dA1.w);          \
        PAIR(a0, bflo(E4.z), bfhi(E4.z), vB.x, vB.y, dB0.x, dB0.y);          \
        PAIR(a1, bflo(E4.z), bfhi(E4.z), vB.x, vB.y, dB1.x, dB1.y);          \
        PAIR(a0, bflo(E4.w), bfhi(E4.w), vB.z, vB.w, dB0.z, dB0.w);          \
        PAIR(a1, bflo(E4.w), bfhi(E4.w), vB.z, vB.w, dB1.z, dB1.w);          \
    } while (0)

#pragma unroll 1
    for (int rep = 0; rep < 4; ++rep) {
        float a0 = 0.f, a1 = 0.f;

        uint4 e4a = Ec[0], e4b;
        for (int cq = 0; cq < 32; cq += 2) {
            e4b = Ec[(size_t)(cq + 1) * 512];
            PROC(e4a, cq);
            if (cq + 2 < 32) e4a = Ec[(size_t)(cq + 2) * 512];
            PROC(e4b, cq + 1);
        }

        prod[0][tid] = -2.0f * a0;
        prod[1][tid] = -2.0f * a1;
        __syncthreads();

        const int w    = tid >> 6;
        const int lane = tid & 63;
        if (w < 2) {
            float p[8];
#pragma unroll
            for (int i = 0; i < 8; ++i) p[i] = prod[w][lane + 64 * i];
            float m = p[0];
#pragma unroll
            for (int i = 1; i < 8; ++i) m = fmaxf(m, p[i]);
#pragma unroll
            for (int off = 1; off < 64; off <<= 1) m = fmaxf(m, __shfl_xor(m, off));
            float s = 0.f;
#pragma unroll
            for (int i = 0; i < 8; ++i) s += __builtin_amdgcn_exp2f((p[i] - m) * LOG2E);
#pragma unroll
            for (int off = 1; off < 64; off <<= 1) s += __shfl_xor(s, off);
            const float lse = m + __builtin_amdgcn_logf(s) * LN2;

            float* o = out + (size_t)(b * ND + n0 + w) * NE;
#pragma unroll
            for (int i = 0; i < 8; ++i) o[lane + 64 * i] = p[i] - lse;
        }
        __syncthreads();   // protect prod reuse across reps
    }
#undef PROC
#undef PAIR
}

// ---------------------------------------------------------------------------
extern "C" void kernel_launch(void* const* d_in, const int* in_sizes, int n_in,
                              void* d_out, int out_size, void* d_ws, size_t ws_size,
                              hipStream_t stream) {
    const float* xdec = (const float*)d_in[0];   // (4,256,256)
    const float* xenc = (const float*)d_in[1];   // (4,512,256)
    const float* w1   = (const float*)d_in[2];   // (256,256)
    const float* w2   = (const float*)d_in[3];   // (256,256)
    const float* v    = (const float*)d_in[4];   // (1,256)
    float* out = (float*)d_out;                  // (4,256,512)

    char* ws = (char*)d_ws;
    uint4* Et4  = (uint4*)ws;                    // [4][32][512] uint4 = 1 MB
    float* Dexp = (float*)(ws + (1u << 20));     // [1024][256] f32 = 1 MB

    dim3 gproj(96, 4);
    proj_kernel<<<gproj, 256, 0, stream>>>(xdec, xenc, w1, w2, Et4, Dexp);
    attn_kernel<<<(BB * ND) / 2, 512, 0, stream>>>(Et4, Dexp, v, out);
}

// Round 14
// 49.093 us; speedup vs baseline: 2.3088x; 2.3088x over previous
//
#include <hip/hip_runtime.h>
#include <math.h>

#define BB 4
#define ND 256
#define NE 512
#define CC 256

#define K2E 2.8853900817779268f   // 2 * log2(e): exp2(K2E*x) = e^{2x}
#define LOG2E 1.4426950408889634f
#define LN2 0.6931471805599453f

typedef unsigned int u32;
typedef unsigned short u16;

__device__ __forceinline__ u16 f2bf(float f) {   // RTNE float->bf16
    u32 u = __builtin_bit_cast(u32, f);
    u += 0x7fffu + ((u >> 16) & 1u);
    return (u16)(u >> 16);
}
__device__ __forceinline__ float bflo(u32 u) { return __builtin_bit_cast(float, u << 16); }
__device__ __forceinline__ float bfhi(u32 u) { return __builtin_bit_cast(float, u & 0xffff0000u); }

// ---------------------------------------------------------------------------
// Projection GEMM + exp epilogue. 128-thr blocks, 32x32 tiles, 768 blocks
// (3 blocks/CU vs R12's 1.5 — grid-starvation fix per R13 counters).
//   enc: Et4[b][cq][e] = uint4 of 4 bf16-c-pair words (8 c per 16B)
//   dec: Dexp[n][c] = exp2(K2E*clamp(x_dec@w2^T,+-9)) row-major f32
// ---------------------------------------------------------------------------
__global__ __launch_bounds__(128) void proj_kernel(
    const float* __restrict__ xdec, const float* __restrict__ xenc,
    const float* __restrict__ w1,   const float* __restrict__ w2,
    uint4* __restrict__ Et4, float* __restrict__ Dexp)
{
    __shared__ float Xs[16][36];   // 32 rows, stride 36 (16B-aligned rows)
    __shared__ float Ws[16][34];   // 32 cols, stride 34 (8B-aligned rows)
    __shared__ u32   T[16][33];    // [cp_local][e_local] transpose staging

    const int row0 = blockIdx.x * 32;     // 0..3071
    const int col0 = blockIdx.y * 32;     // 0..224
    const bool is_enc = (row0 < BB * NE);

    const float* X = is_enc ? xenc : xdec;
    const float* W = is_enc ? w1   : w2;
    const int xrow0 = is_enc ? row0 : (row0 - BB * NE);

    const int tid = threadIdx.x;          // 0..127
    const int lr = tid >> 2, lk = (tid & 3) * 4;   // loader: row/col + k-off
    const int ty = tid >> 4;              // 0..7  (4 rows each)
    const int tx = tid & 15;              // 0..15 (2 cols each)

    float acc[4][2] = {};

    float4 xv = *(const float4*)&X[(xrow0 + lr) * CC + lk];
    float4 wv = *(const float4*)&W[(col0 + lr) * CC + lk];

    for (int k0 = 0; k0 < CC; k0 += 16) {
        __syncthreads();
        Xs[lk + 0][lr] = xv.x; Xs[lk + 1][lr] = xv.y;
        Xs[lk + 2][lr] = xv.z; Xs[lk + 3][lr] = xv.w;
        Ws[lk + 0][lr] = wv.x; Ws[lk + 1][lr] = wv.y;
        Ws[lk + 2][lr] = wv.z; Ws[lk + 3][lr] = wv.w;
        __syncthreads();
        if (k0 + 16 < CC) {   // prefetch next K-tile
            xv = *(const float4*)&X[(xrow0 + lr) * CC + k0 + 16 + lk];
            wv = *(const float4*)&W[(col0 + lr) * CC + k0 + 16 + lk];
        }
#pragma unroll
        for (int k = 0; k < 16; ++k) {
            float4 a = *(const float4*)&Xs[k][ty * 4];
            float2 b = *(const float2*)&Ws[k][tx * 2];
            acc[0][0] += a.x * b.x; acc[0][1] += a.x * b.y;
            acc[1][0] += a.y * b.x; acc[1][1] += a.y * b.y;
            acc[2][0] += a.z * b.x; acc[2][1] += a.z * b.y;
            acc[3][0] += a.w * b.x; acc[3][1] += a.w * b.y;
        }
    }

    float ex[4][2];
#pragma unroll
    for (int i = 0; i < 4; ++i)
#pragma unroll
        for (int j = 0; j < 2; ++j)
            ex[i][j] = __builtin_amdgcn_exp2f(
                K2E * fminf(fmaxf(acc[i][j], -9.f), 9.f));

    if (is_enc) {
        // T[cp_local][e_local]: cp_local = tx (c-pair within 32-col tile)
#pragma unroll
        for (int i = 0; i < 4; ++i)
            T[tx][ty * 4 + i] = (u32)f2bf(ex[i][0]) | ((u32)f2bf(ex[i][1]) << 16);
        __syncthreads();
        const int b   = row0 >> 9;
        const int e0  = row0 & 511;
        const int eL  = tid & 31;        // 0..31
        const int cqL = tid >> 5;        // 0..3
        uint4 w4;
        w4.x = T[cqL * 4 + 0][eL];
        w4.y = T[cqL * 4 + 1][eL];
        w4.z = T[cqL * 4 + 2][eL];
        w4.w = T[cqL * 4 + 3][eL];
        Et4[((size_t)b * 32 + (col0 >> 3) + cqL) * 512 + e0 + eL] = w4;
    } else {
#pragma unroll
        for (int i = 0; i < 4; ++i) {
            float2 o = make_float2(ex[i][0], ex[i][1]);
            *(float2*)&Dexp[(size_t)(xrow0 + ty * 4 + i) * CC + col0 + tx * 2] = o;
        }
    }
}

// ---------------------------------------------------------------------------
// Fused tanh-dot, paired division, 16B E loads. 1024 blocks (4/CU):
// block = (b, n-pair, e-half); 512 thr = 256 e x 2 c-halves; LDS-combine
// partials; raw prod to ws (lsm kernel finishes).
//   p'[n,e] = -2 * sum_c v_c / (1 + E*D)    (sum(v) shift cancels)
// ---------------------------------------------------------------------------
__global__ __launch_bounds__(512) void attn_kernel(
    const uint4* __restrict__ Et4, const float* __restrict__ Dexp,
    const float* __restrict__ v, float* __restrict__ prod)
{
    __shared__ float part[2][2][256];   // [c-half][row][e_local]

    const int blk = blockIdx.x;        // 0..1023
    const int b   = blk >> 8;
    const int rem = blk & 255;
    const int n0  = (rem >> 1) * 2;    // decoder row pair
    const int eh  = rem & 1;           // e-half
    const int tid = threadIdx.x;
    const int eI  = tid & 255;         // e_local
    const int ch  = tid >> 8;          // c-half (wave-uniform)
    const int e   = eh * 256 + eI;

    const float* __restrict__ D0 = Dexp + (size_t)(b * ND + n0) * CC;
    const float* __restrict__ D1 = D0 + CC;
    const uint4* Ec = Et4 + ((size_t)b * 32 + ch * 16) * 512 + e;

    float a0 = 0.f, a1 = 0.f;

#define PAIR(ACC, E0, E1, V0, V1, Dx0, Dx1) do {                             \
        const float _d0 = fmaf((E0), (Dx0), 1.0f);                           \
        const float _d1 = fmaf((E1), (Dx1), 1.0f);                           \
        const float _num = fmaf((V1), _d0, (V0) * _d1);                      \
        ACC = fmaf(_num, __builtin_amdgcn_rcpf(_d0 * _d1), ACC);             \
    } while (0)

#define PROC(E4, CQ) do {                                                    \
        const int c8 = ((CQ) + ch * 16) * 8;                                 \
        const float4 vA  = *(const float4*)&v [c8];                          \
        const float4 vB  = *(const float4*)&v [c8 + 4];                      \
        const float4 dA0 = *(const float4*)&D0[c8];                          \
        const float4 dB0 = *(const float4*)&D0[c8 + 4];                      \
        const float4 dA1 = *(const float4*)&D1[c8];                          \
        const float4 dB1 = *(const float4*)&D1[c8 + 4];                      \
        PAIR(a0, bflo(E4.x), bfhi(E4.x), vA.x, vA.y, dA0.x, dA0.y);          \
        PAIR(a1, bflo(E4.x), bfhi(E4.x), vA.x, vA.y, dA1.x, dA1.y);          \
        PAIR(a0, bflo(E4.y), bfhi(E4.y), vA.z, vA.w, dA0.z, dA0.w);          \
        PAIR(a1, bflo(E4.y), bfhi(E4.y), vA.z, vA.w, dA1.z, dA1.w);          \
        PAIR(a0, bflo(E4.z), bfhi(E4.z), vB.x, vB.y, dB0.x, dB0.y);          \
        PAIR(a1, bflo(E4.z), bfhi(E4.z), vB.x, vB.y, dB1.x, dB1.y);          \
        PAIR(a0, bflo(E4.w), bfhi(E4.w), vB.z, vB.w, dB0.z, dB0.w);          \
        PAIR(a1, bflo(E4.w), bfhi(E4.w), vB.z, vB.w, dB1.z, dB1.w);          \
    } while (0)

    uint4 e4a = Ec[0], e4b;
#pragma unroll 1
    for (int cq = 0; cq < 16; cq += 2) {
        e4b = Ec[(size_t)(cq + 1) * 512];
        PROC(e4a, cq);
        if (cq + 2 < 16) e4a = Ec[(size_t)(cq + 2) * 512];
        PROC(e4b, cq + 1);
    }
#undef PROC
#undef PAIR

    part[ch][0][eI] = a0;
    part[ch][1][eI] = a1;
    __syncthreads();

    // combine c-halves and write raw prod (coalesced)
    const int row = tid >> 8;          // 0..1
    const float val = part[0][row][eI] + part[1][row][eI];
    prod[(size_t)(b * ND + n0 + row) * NE + e] = -2.0f * val;
}

// ---------------------------------------------------------------------------
// log_softmax over e (512) per (b,n) row. One wave per row, 4 rows/block.
// ---------------------------------------------------------------------------
__global__ __launch_bounds__(256) void lsm_kernel(
    const float* __restrict__ prod, float* __restrict__ out)
{
    const int row  = blockIdx.x * 4 + (threadIdx.x >> 6);
    const int lane = threadIdx.x & 63;
    const float* p = prod + (size_t)row * NE;

    float x[8];
#pragma unroll
    for (int i = 0; i < 8; ++i) x[i] = p[lane + 64 * i];
    float m = x[0];
#pragma unroll
    for (int i = 1; i < 8; ++i) m = fmaxf(m, x[i]);
#pragma unroll
    for (int off = 1; off < 64; off <<= 1) m = fmaxf(m, __shfl_xor(m, off));
    float s = 0.f;
#pragma unroll
    for (int i = 0; i < 8; ++i) s += __builtin_amdgcn_exp2f((x[i] - m) * LOG2E);
#pragma unroll
    for (int off = 1; off < 64; off <<= 1) s += __shfl_xor(s, off);
    const float lse = m + __builtin_amdgcn_logf(s) * LN2;

    float* o = out + (size_t)row * NE;
#pragma unroll
    for (int i = 0; i < 8; ++i) o[lane + 64 * i] = x[i] - lse;
}

// ---------------------------------------------------------------------------
extern "C" void kernel_launch(void* const* d_in, const int* in_sizes, int n_in,
                              void* d_out, int out_size, void* d_ws, size_t ws_size,
                              hipStream_t stream) {
    const float* xdec = (const float*)d_in[0];   // (4,256,256)
    const float* xenc = (const float*)d_in[1];   // (4,512,256)
    const float* w1   = (const float*)d_in[2];   // (256,256)
    const float* w2   = (const float*)d_in[3];   // (256,256)
    const float* v    = (const float*)d_in[4];   // (1,256)
    float* out = (float*)d_out;                  // (4,256,512)

    char* ws = (char*)d_ws;
    uint4* Et4  = (uint4*)ws;                    // [4][32][512] uint4 = 1 MB
    float* Dexp = (float*)(ws + (1u << 20));     // [1024][256] f32 = 1 MB
    float* prod = (float*)(ws + (2u << 20));     // [1024][512] f32 = 2 MB

    dim3 gproj(96, 8);                           // 3072/32 rows, 256/32 cols
    proj_kernel<<<gproj, 128, 0, stream>>>(xdec, xenc, w1, w2, Et4, Dexp);
    attn_kernel<<<1024, 512, 0, stream>>>(Et4, Dexp, v, prod);
    lsm_kernel<<<256, 256, 0, stream>>>(prod, out);
}

// Round 15
// 42.219 us; speedup vs baseline: 2.6848x; 1.1628x over previous
//
#include <hip/hip_runtime.h>
#include <math.h>

#define BB 4
#define ND 256
#define NE 512
#define CC 256

#define K2E 2.8853900817779268f   // 2 * log2(e): exp2(K2E*x) = e^{2x}
#define LOG2E 1.4426950408889634f
#define LN2 0.6931471805599453f

typedef unsigned int u32;
typedef unsigned short u16;

__device__ __forceinline__ u16 f2bf(float f) {   // RTNE float->bf16
    u32 u = __builtin_bit_cast(u32, f);
    u += 0x7fffu + ((u >> 16) & 1u);
    return (u16)(u >> 16);
}
__device__ __forceinline__ float bflo(u32 u) { return __builtin_bit_cast(float, u << 16); }
__device__ __forceinline__ float bfhi(u32 u) { return __builtin_bit_cast(float, u & 0xffff0000u); }

// ---------------------------------------------------------------------------
// Projection GEMM + exp epilogue — REVERTED to R12 verbatim (13.2 us, measured
// R11; the R14 retile regressed and is abandoned).
//   enc: Et4[b][cq][e] = uint4 of 4 bf16-c-pair words (8 c per 16B)
//   dec: Dexp[n][c] = exp2(K2E*clamp(x_dec@w2^T,+-9)) row-major f32
// ---------------------------------------------------------------------------
__global__ __launch_bounds__(256) void proj_kernel(
    const float* __restrict__ xdec, const float* __restrict__ xenc,
    const float* __restrict__ w1,   const float* __restrict__ w2,
    uint4* __restrict__ Et4, float* __restrict__ Dexp)
{
    __shared__ float Xs[16][36];
    __shared__ float Ws[16][68];
    __shared__ u32   T[32][33];

    const int row0 = blockIdx.x * 32;
    const int col0 = blockIdx.y * 64;
    const bool is_enc = (row0 < BB * NE);

    const float* X = is_enc ? xenc : xdec;
    const float* W = is_enc ? w1   : w2;
    const int xrow0 = is_enc ? row0 : (row0 - BB * NE);

    const int tid = threadIdx.x;
    const int xr = tid >> 3, xk = (tid & 7) * 2;
    const int wc = tid >> 2, wk = (tid & 3) * 4;
    const int ty = tid >> 5;
    const int tx = tid & 31;

    float acc[4][2] = {};

    float2 xv = *(const float2*)&X[(xrow0 + xr) * CC + xk];
    float4 wv = *(const float4*)&W[(col0 + wc) * CC + wk];

    for (int k0 = 0; k0 < CC; k0 += 16) {
        __syncthreads();
        Xs[xk][xr] = xv.x; Xs[xk + 1][xr] = xv.y;
        Ws[wk][wc] = wv.x; Ws[wk + 1][wc] = wv.y;
        Ws[wk + 2][wc] = wv.z; Ws[wk + 3][wc] = wv.w;
        __syncthreads();
        if (k0 + 16 < CC) {
            xv = *(const float2*)&X[(xrow0 + xr) * CC + k0 + 16 + xk];
            wv = *(const float4*)&W[(col0 + wc) * CC + k0 + 16 + wk];
        }
#pragma unroll
        for (int k = 0; k < 16; ++k) {
            float4 a = *(const float4*)&Xs[k][ty * 4];
            float2 b = *(const float2*)&Ws[k][tx * 2];
            acc[0][0] += a.x * b.x; acc[0][1] += a.x * b.y;
            acc[1][0] += a.y * b.x; acc[1][1] += a.y * b.y;
            acc[2][0] += a.z * b.x; acc[2][1] += a.z * b.y;
            acc[3][0] += a.w * b.x; acc[3][1] += a.w * b.y;
        }
    }

    float ex[4][2];
#pragma unroll
    for (int i = 0; i < 4; ++i)
#pragma unroll
        for (int j = 0; j < 2; ++j)
            ex[i][j] = __builtin_amdgcn_exp2f(
                K2E * fminf(fmaxf(acc[i][j], -9.f), 9.f));

    if (is_enc) {
#pragma unroll
        for (int i = 0; i < 4; ++i)
            T[tx][ty * 4 + i] = (u32)f2bf(ex[i][0]) | ((u32)f2bf(ex[i][1]) << 16);
        __syncthreads();
        const int b   = row0 >> 9;
        const int e0  = row0 & 511;
        const int eL  = tid & 31;
        const int cqL = tid >> 5;
        const int cq0 = col0 >> 3;
        uint4 w4;
        w4.x = T[cqL * 4 + 0][eL];
        w4.y = T[cqL * 4 + 1][eL];
        w4.z = T[cqL * 4 + 2][eL];
        w4.w = T[cqL * 4 + 3][eL];
        Et4[((size_t)b * 32 + cq0 + cqL) * 512 + e0 + eL] = w4;
    } else {
#pragma unroll
        for (int i = 0; i < 4; ++i) {
            float2 o = make_float2(ex[i][0], ex[i][1]);
            *(float2*)&Dexp[(size_t)(xrow0 + ty * 4 + i) * CC + col0 + tx * 2] = o;
        }
    }
}

// ---------------------------------------------------------------------------
// Fused tanh-dot + log_softmax. ONE decoder row per block -> 1024 blocks of
// 512 thr (8 waves/SIMD, 2x R12's occupancy — the R13-counter-backed fix).
// D/v prefetched one cq ahead in registers (R13: 35% idle = unhidden load
// latency, D/v consumed right after issue). E ping-pong kept.
//   p'[n,e] = -2 * sum_c v_c / (1 + E*D)    (sum(v) shift cancels)
//   v0/d0 + v1/d1 = (v0*d1 + v1*d0) / (d0*d1),  d = fma(E, D, 1)
// ---------------------------------------------------------------------------
__global__ __launch_bounds__(512) void attn_kernel(
    const uint4* __restrict__ Et4, const float* __restrict__ Dexp,
    const float* __restrict__ v, float* __restrict__ out)
{
    __shared__ float red[16];

    const int blk = blockIdx.x;       // 0..1023 == b*ND + n
    const int b   = blk >> 8;
    const int tid = threadIdx.x;      // == e

    const float* __restrict__ D = Dexp + (size_t)blk * CC;
    const uint4* Ec = Et4 + (size_t)b * 32 * 512 + tid;

    float a0 = 0.f;

#define PAIR(ACC, E0, E1, V0, V1, Dx0, Dx1) do {                             \
        const float _d0 = fmaf((E0), (Dx0), 1.0f);                           \
        const float _d1 = fmaf((E1), (Dx1), 1.0f);                           \
        const float _num = fmaf((V1), _d0, (V0) * _d1);                      \
        ACC = fmaf(_num, __builtin_amdgcn_rcpf(_d0 * _d1), ACC);             \
    } while (0)

#define PROC(E4, VA, VB, DA, DB) do {                                        \
        PAIR(a0, bflo(E4.x), bfhi(E4.x), VA.x, VA.y, DA.x, DA.y);            \
        PAIR(a0, bflo(E4.y), bfhi(E4.y), VA.z, VA.w, DA.z, DA.w);            \
        PAIR(a0, bflo(E4.z), bfhi(E4.z), VB.x, VB.y, DB.x, DB.y);            \
        PAIR(a0, bflo(E4.w), bfhi(E4.w), VB.z, VB.w, DB.z, DB.w);            \
    } while (0)

    // prefetch cq=0
    uint4  e4 = Ec[0];
    float4 vA = *(const float4*)&v[0], vB = *(const float4*)&v[4];
    float4 dA = *(const float4*)&D[0], dB = *(const float4*)&D[4];

#pragma unroll 2
    for (int cq = 0; cq < 32; ++cq) {
        uint4 e4n; float4 vAn, vBn, dAn, dBn;
        if (cq + 1 < 32) {                       // prefetch cq+1
            const int c8 = (cq + 1) * 8;
            e4n = Ec[(size_t)(cq + 1) * 512];
            vAn = *(const float4*)&v[c8]; vBn = *(const float4*)&v[c8 + 4];
            dAn = *(const float4*)&D[c8]; dBn = *(const float4*)&D[c8 + 4];
        }
        PROC(e4, vA, vB, dA, dB);
        e4 = e4n; vA = vAn; vB = vBn; dA = dAn; dB = dBn;
    }
#undef PROC
#undef PAIR

    const float p = -2.0f * a0;

    // log_softmax over the block's 512 e (each thread holds one value)
    const int w    = tid >> 6;
    const int lane = tid & 63;

    float m = p;
#pragma unroll
    for (int off = 1; off < 64; off <<= 1) m = fmaxf(m, __shfl_xor(m, off));
    if (lane == 0) red[w] = m;
    __syncthreads();
    m = red[0];
#pragma unroll
    for (int i = 1; i < 8; ++i) m = fmaxf(m, red[i]);

    float s = __builtin_amdgcn_exp2f((p - m) * LOG2E);
#pragma unroll
    for (int off = 1; off < 64; off <<= 1) s += __shfl_xor(s, off);
    if (lane == 0) red[8 + w] = s;
    __syncthreads();
    s = red[8];
#pragma unroll
    for (int i = 1; i < 8; ++i) s += red[8 + i];

    out[(size_t)blk * NE + tid] = p - (m + __builtin_amdgcn_logf(s) * LN2);
}

// ---------------------------------------------------------------------------
extern "C" void kernel_launch(void* const* d_in, const int* in_sizes, int n_in,
                              void* d_out, int out_size, void* d_ws, size_t ws_size,
                              hipStream_t stream) {
    const float* xdec = (const float*)d_in[0];   // (4,256,256)
    const float* xenc = (const float*)d_in[1];   // (4,512,256)
    const float* w1   = (const float*)d_in[2];   // (256,256)
    const float* w2   = (const float*)d_in[3];   // (256,256)
    const float* v    = (const float*)d_in[4];   // (1,256)
    float* out = (float*)d_out;                  // (4,256,512)

    char* ws = (char*)d_ws;
    uint4* Et4  = (uint4*)ws;                    // [4][32][512] uint4 = 1 MB
    float* Dexp = (float*)(ws + (1u << 20));     // [1024][256] f32 = 1 MB

    dim3 gproj(96, 4);
    proj_kernel<<<gproj, 256, 0, stream>>>(xdec, xenc, w1, w2, Et4, Dexp);
    attn_kernel<<<BB * ND, 512, 0, stream>>>(Et4, Dexp, v, out);
}

// Round 16
// 36.500 us; speedup vs baseline: 3.1054x; 1.1567x over previous
//
#include <hip/hip_runtime.h>
#include <math.h>

#define BB 4
#define ND 256
#define NE 512
#define CC 256

#define K2E 2.8853900817779268f   // 2 * log2(e): exp2(K2E*x) = e^{2x}
#define LOG2E 1.4426950408889634f
#define LN2 0.6931471805599453f

typedef unsigned int u32;
typedef unsigned short u16;

__device__ __forceinline__ u16 f2bf(float f) {   // RTNE float->bf16
    u32 u = __builtin_bit_cast(u32, f);
    u += 0x7fffu + ((u >> 16) & 1u);
    return (u16)(u >> 16);
}
__device__ __forceinline__ float bflo(u32 u) { return __builtin_bit_cast(float, u << 16); }
__device__ __forceinline__ float bfhi(u32 u) { return __builtin_bit_cast(float, u & 0xffff0000u); }

// ---------------------------------------------------------------------------
// Projection GEMM + exp epilogue. R1's 64x64 tile (acc[4][4], 16 FMA/k/thread
// — 2x the FMA-per-ds_read of the 32-row tile that measured 13.2us in R11)
// + register prefetch + bf16-pack transposed epilogue for enc.
//   enc: Et4[b][cq][e] = uint4 of 4 bf16-c-pair words (8 c per 16B)
//   dec: Dexp[n][c] = exp2(K2E*clamp(x_dec@w2^T,+-9)) row-major f32
// ---------------------------------------------------------------------------
__global__ __launch_bounds__(256) void proj_kernel(
    const float* __restrict__ xdec, const float* __restrict__ xenc,
    const float* __restrict__ w1,   const float* __restrict__ w2,
    uint4* __restrict__ Et4, float* __restrict__ Dexp)
{
    __shared__ float Xs[16][68];
    __shared__ float Ws[16][68];
    __shared__ u32   T[32][65];    // [cp_local][e_local] transpose staging

    const int row0 = blockIdx.x * 64;
    const int col0 = blockIdx.y * 64;
    const bool is_enc = (row0 < BB * NE);

    const float* X = is_enc ? xenc : xdec;
    const float* W = is_enc ? w1   : w2;
    const int xrow0 = is_enc ? row0 : (row0 - BB * NE);

    const int tid = threadIdx.x;
    const int lr = tid >> 2;           // 0..63   loader row/col
    const int lk = (tid & 3) << 2;     // 0,4,8,12
    const int ty = tid >> 4;           // 0..15   (4 rows each)
    const int tx = tid & 15;           // 0..15   (4 cols each)

    float acc[4][4] = {};

    float4 xv = *(const float4*)&X[(xrow0 + lr) * CC + lk];
    float4 wv = *(const float4*)&W[(col0 + lr) * CC + lk];

    for (int k0 = 0; k0 < CC; k0 += 16) {
        __syncthreads();
        Xs[lk + 0][lr] = xv.x; Xs[lk + 1][lr] = xv.y;
        Xs[lk + 2][lr] = xv.z; Xs[lk + 3][lr] = xv.w;
        Ws[lk + 0][lr] = wv.x; Ws[lk + 1][lr] = wv.y;
        Ws[lk + 2][lr] = wv.z; Ws[lk + 3][lr] = wv.w;
        __syncthreads();
        if (k0 + 16 < CC) {            // prefetch next K-tile
            xv = *(const float4*)&X[(xrow0 + lr) * CC + k0 + 16 + lk];
            wv = *(const float4*)&W[(col0 + lr) * CC + k0 + 16 + lk];
        }
#pragma unroll
        for (int k = 0; k < 16; ++k) {
            float4 a = *(const float4*)&Xs[k][ty * 4];
            float4 b = *(const float4*)&Ws[k][tx * 4];
            acc[0][0] += a.x * b.x; acc[0][1] += a.x * b.y;
            acc[0][2] += a.x * b.z; acc[0][3] += a.x * b.w;
            acc[1][0] += a.y * b.x; acc[1][1] += a.y * b.y;
            acc[1][2] += a.y * b.z; acc[1][3] += a.y * b.w;
            acc[2][0] += a.z * b.x; acc[2][1] += a.z * b.y;
            acc[2][2] += a.z * b.z; acc[2][3] += a.z * b.w;
            acc[3][0] += a.w * b.x; acc[3][1] += a.w * b.y;
            acc[3][2] += a.w * b.z; acc[3][3] += a.w * b.w;
        }
    }

    float ex[4][4];
#pragma unroll
    for (int i = 0; i < 4; ++i)
#pragma unroll
        for (int j = 0; j < 4; ++j)
            ex[i][j] = __builtin_amdgcn_exp2f(
                K2E * fminf(fmaxf(acc[i][j], -9.f), 9.f));

    if (is_enc) {
        // pack c-pairs, stage transposed: T[cp_local][e_local]
        // thread cols tx*4..tx*4+3 -> cp_local = tx*2, tx*2+1
#pragma unroll
        for (int i = 0; i < 4; ++i) {
            T[tx * 2 + 0][ty * 4 + i] = (u32)f2bf(ex[i][0]) | ((u32)f2bf(ex[i][1]) << 16);
            T[tx * 2 + 1][ty * 4 + i] = (u32)f2bf(ex[i][2]) | ((u32)f2bf(ex[i][3]) << 16);
        }
        __syncthreads();
        const int b   = row0 >> 9;
        const int e0  = row0 & 511;
        const int eL  = tid & 63;        // e_local
        const int cqL = tid >> 6;        // 0..3
#pragma unroll
        for (int r = 0; r < 2; ++r) {
            const int cq = cqL + r * 4;  // 0..7 within 64-col tile
            uint4 w4;
            w4.x = T[cq * 4 + 0][eL];
            w4.y = T[cq * 4 + 1][eL];
            w4.z = T[cq * 4 + 2][eL];
            w4.w = T[cq * 4 + 3][eL];
            Et4[((size_t)b * 32 + (col0 >> 3) + cq) * 512 + e0 + eL] = w4;
        }
    } else {
#pragma unroll
        for (int i = 0; i < 4; ++i) {
            float4 o = make_float4(ex[i][0], ex[i][1], ex[i][2], ex[i][3]);
            *(float4*)&Dexp[(size_t)(xrow0 + ty * 4 + i) * CC + col0 + tx * 4] = o;
        }
    }
}

// ---------------------------------------------------------------------------
// Fused tanh-dot + log_softmax — R12 VERBATIM (best measured: ~17-20us).
//   p'[n,e] = -2 * sum_c v_c / (1 + E*D)    (sum(v) shift cancels)
//   v0/d0 + v1/d1 = (v0*d1 + v1*d0) / (d0*d1),  d = fma(E, D, 1)
// 512 thr (tid = e), 2 decoder rows/block, 512 blocks.
// ---------------------------------------------------------------------------
__global__ __launch_bounds__(512) void attn_kernel(
    const uint4* __restrict__ Et4, const float* __restrict__ Dexp,
    const float* __restrict__ v, float* __restrict__ out)
{
    __shared__ float prod[2][NE];

    const int blk = blockIdx.x;       // 0..511
    const int b   = blk >> 7;
    const int n0  = (blk & 127) * 2;
    const int tid = threadIdx.x;      // == e

    const float* __restrict__ D0 = Dexp + (size_t)(b * ND + n0) * CC;
    const float* __restrict__ D1 = D0 + CC;
    const uint4* Ec = Et4 + (size_t)b * 32 * 512 + tid;

    float a0 = 0.f, a1 = 0.f;

#define PAIR(ACC, E0, E1, V0, V1, Dx0, Dx1) do {                             \
        const float _d0 = fmaf((E0), (Dx0), 1.0f);                           \
        const float _d1 = fmaf((E1), (Dx1), 1.0f);                           \
        const float _num = fmaf((V1), _d0, (V0) * _d1);                      \
        ACC = fmaf(_num, __builtin_amdgcn_rcpf(_d0 * _d1), ACC);             \
    } while (0)

#define PROC(E4, CQ) do {                                                    \
        const int c8 = (CQ) * 8;                                             \
        const float4 vA  = *(const float4*)&v [c8];                          \
        const float4 vB  = *(const float4*)&v [c8 + 4];                      \
        const float4 dA0 = *(const float4*)&D0[c8];                          \
        const float4 dB0 = *(const float4*)&D0[c8 + 4];                      \
        const float4 dA1 = *(const float4*)&D1[c8];                          \
        const float4 dB1 = *(const float4*)&D1[c8 + 4];                      \
        PAIR(a0, bflo(E4.x), bfhi(E4.x), vA.x, vA.y, dA0.x, dA0.y);          \
        PAIR(a1, bflo(E4.x), bfhi(E4.x), vA.x, vA.y, dA1.x, dA1.y);          \
        PAIR(a0, bflo(E4.y), bfhi(E4.y), vA.z, vA.w, dA0.z, dA0.w);          \
        PAIR(a1, bflo(E4.y), bfhi(E4.y), vA.z, vA.w, dA1.z, dA1.w);          \
        PAIR(a0, bflo(E4.z), bfhi(E4.z), vB.x, vB.y, dB0.x, dB0.y);          \
        PAIR(a1, bflo(E4.z), bfhi(E4.z), vB.x, vB.y, dB1.x, dB1.y);          \
        PAIR(a0, bflo(E4.w), bfhi(E4.w), vB.z, vB.w, dB0.z, dB0.w);          \
        PAIR(a1, bflo(E4.w), bfhi(E4.w), vB.z, vB.w, dB1.z, dB1.w);          \
    } while (0)

    uint4 e4a = Ec[0], e4b;
    for (int cq = 0; cq < 32; cq += 2) {
        e4b = Ec[(size_t)(cq + 1) * 512];
        PROC(e4a, cq);
        if (cq + 2 < 32) e4a = Ec[(size_t)(cq + 2) * 512];
        PROC(e4b, cq + 1);
    }
#undef PROC
#undef PAIR

    prod[0][tid] = -2.0f * a0;
    prod[1][tid] = -2.0f * a1;
    __syncthreads();

    // log_softmax: wave w (w<2) handles decoder row n0+w
    const int w    = tid >> 6;
    const int lane = tid & 63;
    if (w < 2) {
        float p[8];
#pragma unroll
        for (int i = 0; i < 8; ++i) p[i] = prod[w][lane + 64 * i];
        float m = p[0];
#pragma unroll
        for (int i = 1; i < 8; ++i) m = fmaxf(m, p[i]);
#pragma unroll
        for (int off = 1; off < 64; off <<= 1) m = fmaxf(m, __shfl_xor(m, off));
        float s = 0.f;
#pragma unroll
        for (int i = 0; i < 8; ++i) s += __builtin_amdgcn_exp2f((p[i] - m) * LOG2E);
#pragma unroll
        for (int off = 1; off < 64; off <<= 1) s += __shfl_xor(s, off);
        const float lse = m + __builtin_amdgcn_logf(s) * LN2;

        float* o = out + (size_t)(b * ND + n0 + w) * NE;
#pragma unroll
        for (int i = 0; i < 8; ++i) o[lane + 64 * i] = p[i] - lse;
    }
}

// ---------------------------------------------------------------------------
extern "C" void kernel_launch(void* const* d_in, const int* in_sizes, int n_in,
                              void* d_out, int out_size, void* d_ws, size_t ws_size,
                              hipStream_t stream) {
    const float* xdec = (const float*)d_in[0];   // (4,256,256)
    const float* xenc = (const float*)d_in[1];   // (4,512,256)
    const float* w1   = (const float*)d_in[2];   // (256,256)
    const float* w2   = (const float*)d_in[3];   // (256,256)
    const float* v    = (const float*)d_in[4];   // (1,256)
    float* out = (float*)d_out;                  // (4,256,512)

    char* ws = (char*)d_ws;
    uint4* Et4  = (uint4*)ws;                    // [4][32][512] uint4 = 1 MB
    float* Dexp = (float*)(ws + (1u << 20));     // [1024][256] f32 = 1 MB

    dim3 gproj(48, 4);                           // 3072/64 rows, 256/64 cols
    proj_kernel<<<gproj, 256, 0, stream>>>(xdec, xenc, w1, w2, Et4, Dexp);
    attn_kernel<<<(BB * ND) / 2, 512, 0, stream>>>(Et4, Dexp, v, out);
}

// Round 17
// 35.051 us; speedup vs baseline: 3.2337x; 1.0413x over previous
//
#include <hip/hip_runtime.h>
#include <math.h>

#define BB 4
#define ND 256
#define NE 512
#define CC 256

#define K2E 2.8853900817779268f   // 2 * log2(e): exp2(K2E*x) = e^{2x}
#define LOG2E 1.4426950408889634f
#define LN2 0.6931471805599453f

typedef unsigned int u32;
typedef unsigned short u16;
typedef __attribute__((ext_vector_type(8))) short bf16x8;   // 8 bf16 (4 VGPR)
typedef __attribute__((ext_vector_type(4))) float f32x4;
typedef __attribute__((ext_vector_type(4))) u32   u32x4;

__device__ __forceinline__ float bflo(u32 u) { return __builtin_bit_cast(float, u << 16); }
__device__ __forceinline__ float bfhi(u32 u) { return __builtin_bit_cast(float, u & 0xffff0000u); }

// pack 2 f32 -> 1 u32 of 2 bf16 (lo in [15:0], hi in [31:16])
__device__ __forceinline__ u32 cvt_pk(float lo, float hi) {
    u32 r;
    asm("v_cvt_pk_bf16_f32 %0, %1, %2" : "=v"(r) : "v"(lo), "v"(hi));
    return r;
}

__device__ __forceinline__ bf16x8 mk_frag(float4 f0, float4 f1) {
    u32x4 q;
    q.x = cvt_pk(f0.x, f0.y);
    q.y = cvt_pk(f0.z, f0.w);
    q.z = cvt_pk(f1.x, f1.y);
    q.w = cvt_pk(f1.z, f1.w);
    return __builtin_bit_cast(bf16x8, q);
}

// ---------------------------------------------------------------------------
// MFMA projection: Y = X @ W^T via v_mfma_f32_16x16x32_bf16, one 16x16 tile
// per wave, K-loop 8 steps, NO LDS staging / NO barriers in the K-loop.
// A-frag (X) lane l: row = l&15, k = (l>>4)*8 + j (8 contiguous f32 -> bf16).
// B-frag (W) lane l: col = l&15, same k packing (Y = X W^T means B[k][n]=W[n][k]).
// C/D: col = lane&15, row = (lane>>4)*4 + reg  [m89-verified].
// Block = 4 waves stacked on M (64 rows x 16 cols); grid (48,16) = 768 blocks.
//   enc rows (0..2047):  Et4[b][cq][e] = uint4 of 4 bf16-c-pair words,
//                        packed-transposed via small LDS stage (R12 layout).
//   dec rows (2048..3071): Dexp[n][c] = exp2(K2E*clamp(.,+-9)) row-major f32.
// ---------------------------------------------------------------------------
__global__ __launch_bounds__(256) void proj_kernel(
    const float* __restrict__ xdec, const float* __restrict__ xenc,
    const float* __restrict__ w1,   const float* __restrict__ w2,
    uint4* __restrict__ Et4, float* __restrict__ Dexp)
{
    __shared__ float Ct[64][17];   // C staging for enc pack-transpose

    const int row0 = blockIdx.x * 64;     // M base (0..3071)
    const int col0 = blockIdx.y * 16;     // N base (0..240)
    const bool is_enc = (row0 < BB * NE);

    const float* X = is_enc ? xenc : xdec;
    const float* W = is_enc ? w1   : w2;
    const int xrow0 = is_enc ? row0 : (row0 - BB * NE);

    const int tid = threadIdx.x;
    const int wv  = tid >> 6;        // wave 0..3
    const int l   = tid & 63;
    const int lm  = l & 15;          // fragment row (A) / col (B)
    const int kg  = l >> 4;          // k-group 0..3

    const float* Arow = X + (size_t)(xrow0 + wv * 16 + lm) * CC + kg * 8;
    const float* Brow = W + (size_t)(col0 + lm) * CC + kg * 8;

    f32x4 acc = {0.f, 0.f, 0.f, 0.f};
#pragma unroll
    for (int ks = 0; ks < 8; ++ks) {
        const float* ap = Arow + ks * 32;
        const float* bp = Brow + ks * 32;
        bf16x8 af = mk_frag(*(const float4*)ap, *(const float4*)(ap + 4));
        bf16x8 bf = mk_frag(*(const float4*)bp, *(const float4*)(bp + 4));
        acc = __builtin_amdgcn_mfma_f32_16x16x32_bf16(af, bf, acc, 0, 0, 0);
    }

    float ex[4];
#pragma unroll
    for (int i = 0; i < 4; ++i)
        ex[i] = __builtin_amdgcn_exp2f(
            K2E * fminf(fmaxf(acc[i], -9.f), 9.f));

    if (is_enc) {
        // stage C: row (e_local) = wv*16 + kg*4 + i, col (c_local) = lm
#pragma unroll
        for (int i = 0; i < 4; ++i)
            Ct[wv * 16 + kg * 4 + i][lm] = ex[i];
        __syncthreads();
        if (tid < 128) {
            const int e   = tid & 63;
            const int cqL = tid >> 6;        // 0..1 (this block's 2 cq cols)
            const int b   = row0 >> 9;
            const int e0  = row0 & 511;
            const float* cr = &Ct[e][cqL * 8];
            u32x4 q;
            q.x = cvt_pk(cr[0], cr[1]);
            q.y = cvt_pk(cr[2], cr[3]);
            q.z = cvt_pk(cr[4], cr[5]);
            q.w = cvt_pk(cr[6], cr[7]);
            Et4[((size_t)b * 32 + (col0 >> 3) + cqL) * 512 + e0 + e] =
                __builtin_bit_cast(uint4, q);
        }
    } else {
        const int n = xrow0 + wv * 16 + kg * 4;
#pragma unroll
        for (int i = 0; i < 4; ++i)
            Dexp[(size_t)(n + i) * CC + col0 + lm] = ex[i];
    }
}

// ---------------------------------------------------------------------------
// Fused tanh-dot + log_softmax — R12/R16 VERBATIM (best measured ~17-20us).
//   p'[n,e] = -2 * sum_c v_c / (1 + E*D)    (sum(v) shift cancels)
//   v0/d0 + v1/d1 = (v0*d1 + v1*d0) / (d0*d1),  d = fma(E, D, 1)
// 512 thr (tid = e), 2 decoder rows/block, 512 blocks.
// ---------------------------------------------------------------------------
__global__ __launch_bounds__(512) void attn_kernel(
    const uint4* __restrict__ Et4, const float* __restrict__ Dexp,
    const float* __restrict__ v, float* __restrict__ out)
{
    __shared__ float prod[2][NE];

    const int blk = blockIdx.x;       // 0..511
    const int b   = blk >> 7;
    const int n0  = (blk & 127) * 2;
    const int tid = threadIdx.x;      // == e

    const float* __restrict__ D0 = Dexp + (size_t)(b * ND + n0) * CC;
    const float* __restrict__ D1 = D0 + CC;
    const uint4* Ec = Et4 + (size_t)b * 32 * 512 + tid;

    float a0 = 0.f, a1 = 0.f;

#define PAIR(ACC, E0, E1, V0, V1, Dx0, Dx1) do {                             \
        const float _d0 = fmaf((E0), (Dx0), 1.0f);                           \
        const float _d1 = fmaf((E1), (Dx1), 1.0f);                           \
        const float _num = fmaf((V1), _d0, (V0) * _d1);                      \
        ACC = fmaf(_num, __builtin_amdgcn_rcpf(_d0 * _d1), ACC);             \
    } while (0)

#define PROC(E4, CQ) do {                                                    \
        const int c8 = (CQ) * 8;                                             \
        const float4 vA  = *(const float4*)&v [c8];                          \
        const float4 vB  = *(const float4*)&v [c8 + 4];                      \
        const float4 dA0 = *(const float4*)&D0[c8];                          \
        const float4 dB0 = *(const float4*)&D0[c8 + 4];                      \
        const float4 dA1 = *(const float4*)&D1[c8];                          \
        const float4 dB1 = *(const float4*)&D1[c8 + 4];                      \
        PAIR(a0, bflo(E4.x), bfhi(E4.x), vA.x, vA.y, dA0.x, dA0.y);          \
        PAIR(a1, bflo(E4.x), bfhi(E4.x), vA.x, vA.y, dA1.x, dA1.y);          \
        PAIR(a0, bflo(E4.y), bfhi(E4.y), vA.z, vA.w, dA0.z, dA0.w);          \
        PAIR(a1, bflo(E4.y), bfhi(E4.y), vA.z, vA.w, dA1.z, dA1.w);          \
        PAIR(a0, bflo(E4.z), bfhi(E4.z), vB.x, vB.y, dB0.x, dB0.y);          \
        PAIR(a1, bflo(E4.z), bfhi(E4.z), vB.x, vB.y, dB1.x, dB1.y);          \
        PAIR(a0, bflo(E4.w), bfhi(E4.w), vB.z, vB.w, dB0.z, dB0.w);          \
        PAIR(a1, bflo(E4.w), bfhi(E4.w), vB.z, vB.w, dB1.z, dB1.w);          \
    } while (0)

    uint4 e4a = Ec[0], e4b;
    for (int cq = 0; cq < 32; cq += 2) {
        e4b = Ec[(size_t)(cq + 1) * 512];
        PROC(e4a, cq);
        if (cq + 2 < 32) e4a = Ec[(size_t)(cq + 2) * 512];
        PROC(e4b, cq + 1);
    }
#undef PROC
#undef PAIR

    prod[0][tid] = -2.0f * a0;
    prod[1][tid] = -2.0f * a1;
    __syncthreads();

    // log_softmax: wave w (w<2) handles decoder row n0+w
    const int w    = tid >> 6;
    const int lane = tid & 63;
    if (w < 2) {
        float p[8];
#pragma unroll
        for (int i = 0; i < 8; ++i) p[i] = prod[w][lane + 64 * i];
        float m = p[0];
#pragma unroll
        for (int i = 1; i < 8; ++i) m = fmaxf(m, p[i]);
#pragma unroll
        for (int off = 1; off < 64; off <<= 1) m = fmaxf(m, __shfl_xor(m, off));
        float s = 0.f;
#pragma unroll
        for (int i = 0; i < 8; ++i) s += __builtin_amdgcn_exp2f((p[i] - m) * LOG2E);
#pragma unroll
        for (int off = 1; off < 64; off <<= 1) s += __shfl_xor(s, off);
        const float lse = m + __builtin_amdgcn_logf(s) * LN2;

        float* o = out + (size_t)(b * ND + n0 + w) * NE;
#pragma unroll
        for (int i = 0; i < 8; ++i) o[lane + 64 * i] = p[i] - lse;
    }
}

// ---------------------------------------------------------------------------
extern "C" void kernel_launch(void* const* d_in, const int* in_sizes, int n_in,
                              void* d_out, int out_size, void* d_ws, size_t ws_size,
                              hipStream_t stream) {
    const float* xdec = (const float*)d_in[0];   // (4,256,256)
    const float* xenc = (const float*)d_in[1];   // (4,512,256)
    const float* w1   = (const float*)d_in[2];   // (256,256)
    const float* w2   = (const float*)d_in[3];   // (256,256)
    const float* v    = (const float*)d_in[4];   // (1,256)
    float* out = (float*)d_out;                  // (4,256,512)

    char* ws = (char*)d_ws;
    uint4* Et4  = (uint4*)ws;                    // [4][32][512] uint4 = 1 MB
    float* Dexp = (float*)(ws + (1u << 20));     // [1024][256] f32 = 1 MB

    dim3 gproj(48, 16);                          // 3072/64 rows, 256/16 cols
    proj_kernel<<<gproj, 256, 0, stream>>>(xdec, xenc, w1, w2, Et4, Dexp);
    attn_kernel<<<(BB * ND) / 2, 512, 0, stream>>>(Et4, Dexp, v, out);
}